// Round 14
// baseline (203.959 us; speedup 1.0000x reference)
//
#include <hip/hip_runtime.h>
#include <cstdint>

// ---------- types ----------
using bx8 = __attribute__((ext_vector_type(8))) __bf16;   // MFMA A/B fragment (8 bf16)
using us8 = __attribute__((ext_vector_type(8))) unsigned short;
using us4 = __attribute__((ext_vector_type(4))) unsigned short;
using fl8 = __attribute__((ext_vector_type(8))) float;
using fx4 = __attribute__((ext_vector_type(4))) float;    // MFMA C/D fragment

static __device__ inline unsigned short f2bf(float f) {
  unsigned u = __builtin_bit_cast(unsigned, f);
  unsigned r = 0x7FFFu + ((u >> 16) & 1u);   // round-to-nearest-even
  return (unsigned short)((u + r) >> 16);
}
static __device__ inline float bf2f(unsigned short s) {
  return __builtin_bit_cast(float, (unsigned)s << 16);
}

static __device__ inline fx4 mfma16(bx8 a, bx8 b, fx4 c) {
  return __builtin_amdgcn_mfma_f32_16x16x32_bf16(a, b, c, 0, 0, 0);
}

// async global->LDS, 16B/lane; dest = wave-uniform base + lane*16 (R9-proven w/ drain)
static __device__ inline void gload16(const void* g, void* lds) {
  __builtin_amdgcn_global_load_lds(
      (const __attribute__((address_space(1))) void*)g,
      (__attribute__((address_space(3))) void*)lds,
      16, 0, 0);
}
#define VMCNT(n) asm volatile("s_waitcnt vmcnt(" #n ")" ::: "memory")
// raw barrier (does NOT drain vmcnt, unlike __syncthreads) + compiler fences
static __device__ inline void wave_barrier() {
  __builtin_amdgcn_sched_barrier(0);
  __builtin_amdgcn_s_barrier();
  __builtin_amdgcn_sched_barrier(0);
}

// DPP row_ror:k (VALU-latency cross-lane)
#define DPP_ROR(x, k) __builtin_bit_cast(float, __builtin_amdgcn_update_dpp( \
    __builtin_bit_cast(int, x), __builtin_bit_cast(int, x), 0x120 | (k), 0xF, 0xF, false))

static __device__ inline float rowmax16(float v) {
  v = fmaxf(v, DPP_ROR(v, 1));
  v = fmaxf(v, DPP_ROR(v, 2));
  v = fmaxf(v, DPP_ROR(v, 4));
  v = fmaxf(v, DPP_ROR(v, 8));
  return v;
}
static __device__ inline float rowsum16(float v) {
  v += DPP_ROR(v, 1);
  v += DPP_ROR(v, 2);
  v += DPP_ROR(v, 4);
  v += DPP_ROR(v, 8);
  return v;
}

// ---------- fp32 -> bf16 convert (R4-proven) ----------
__global__ __launch_bounds__(256) void f2b_kernel(const float* __restrict__ in,
                                                  unsigned short* __restrict__ out,
                                                  int n) {
  int i = (blockIdx.x * 256 + threadIdx.x) * 4;
  if (i >= n) return;
  float4 v = *reinterpret_cast<const float4*>(in + i);
  ushort4 o;
  o.x = f2bf(v.x); o.y = f2bf(v.y); o.z = f2bf(v.z); o.w = f2bf(v.w);
  *reinterpret_cast<ushort4*>(out + i) = o;
}

// ================= GEMM1: 256x256 tile, BK=32, depth-3 counted-vmcnt pipeline (R10-proven) =================
__global__ __launch_bounds__(512, 2) void gemm256(const unsigned short* __restrict__ A,
                                                  const unsigned short* __restrict__ B,
                                                  unsigned short* __restrict__ C,
                                                  int M, int N, int K) {
  __shared__ unsigned short lds[4][2][256 * 32];   // [buf][A/B][row*32 + col]

  const int tid = threadIdx.x;
  const int w = tid >> 6, l = tid & 63;
  const int l16 = l & 15, lg = l >> 4;
  const int wr = w >> 2, wc = w & 3;
  const long mb = (long)blockIdx.y * 256, nb = (long)blockIdx.x * 256;

  const int lr = l >> 2;
  const int sw = (((l & 3) ^ (lr & 3)) * 8);       // pre-swizzled col (elements)
  const unsigned short* Ag = A + (mb + w * 32 + lr) * (long)K + sw;
  const unsigned short* Bg = B + (nb + w * 32 + lr) * (long)K + sw;

  const int rdcol = ((lg ^ (l16 & 3)) * 16);

  const fx4 fz = {0.f, 0.f, 0.f, 0.f};
  fx4 acc[8][4];
#pragma unroll
  for (int i = 0; i < 8; ++i)
#pragma unroll
    for (int j = 0; j < 4; ++j) acc[i][j] = fz;

  const int nt = K >> 5;   // K/32 tiles

  auto stage = [&](int tp) {
    const int db = tp & 3;
    const unsigned short* as = Ag + tp * 32;
    const unsigned short* bs = Bg + tp * 32;
    char* al = (char*)&lds[db][0][0] + w * 32 * 64;
    char* bl = (char*)&lds[db][1][0] + w * 32 * 64;
    gload16(as, al);
    gload16(as + 16 * (long)K, al + 1024);
    gload16(bs, bl);
    gload16(bs + 16 * (long)K, bl + 1024);
  };

  auto compute = [&](int bt) {
    const char* Ab = (const char*)&lds[bt][0][0] + (wr * 128 + l16) * 64 + rdcol;
    const char* Bb = (const char*)&lds[bt][1][0] + (wc * 64 + l16) * 64 + rdcol;
    bx8 bf[4];
#pragma unroll
    for (int nf = 0; nf < 4; ++nf)
      bf[nf] = *reinterpret_cast<const bx8*>(Bb + nf * 1024);
    __builtin_amdgcn_s_setprio(1);
#pragma unroll
    for (int mf = 0; mf < 8; ++mf) {
      bx8 av = *reinterpret_cast<const bx8*>(Ab + mf * 1024);
#pragma unroll
      for (int nf = 0; nf < 4; ++nf)
        acc[mf][nf] = mfma16(av, bf[nf], acc[mf][nf]);
    }
    __builtin_amdgcn_s_setprio(0);
  };

  stage(0); stage(1); stage(2);
  VMCNT(8);
  wave_barrier();

  int t = 0;
  for (; t < nt - 3; ++t) {
    stage(t + 3);
    compute(t & 3);
    VMCNT(8);
    wave_barrier();
  }
  compute(t & 3); VMCNT(4); wave_barrier(); ++t;
  compute(t & 3); VMCNT(0); wave_barrier(); ++t;
  compute(t & 3);

#pragma unroll
  for (int mf = 0; mf < 8; ++mf)
#pragma unroll
    for (int nf = 0; nf < 4; ++nf)
#pragma unroll
      for (int r = 0; r < 4; ++r) {
        const long row = mb + wr * 128 + mf * 16 + lg * 4 + r;
        const long col = nb + wc * 64 + nf * 16 + l16;
        C[row * N + col] = f2bf(acc[mf][nf][r]);
      }
}

// ---------- staging-reg type per operand dtype (R8-proven fold GEMM) ----------
template <typename T> struct RegOf { using type = us8; };
template <> struct RegOf<float>  { using type = fl8; };

template <typename T>
static __device__ inline typename RegOf<T>::type load8(const T* p) {
  return *reinterpret_cast<const typename RegOf<T>::type*>(p);
}
static __device__ inline us8 toBf(us8 v) { return v; }
static __device__ inline us8 toBf(fl8 f) {
  us8 o;
#pragma unroll
  for (int j = 0; j < 8; ++j) {
    __bf16 b = (__bf16)f[j];
    o[j] = __builtin_bit_cast(unsigned short, b);
  }
  return o;
}

// ---------- GEMM2: R8-proven 128x128 reg-staged fold kernel ----------
template <typename TA, typename TB, bool F32OUT>
__global__ __launch_bounds__(256) void gemm_bt(const TA* __restrict__ A,
                                               const TB* __restrict__ B,
                                               void* __restrict__ Cp,
                                               int M, int N, int K) {
  __shared__ alignas(16) unsigned short As[128 * 64];
  __shared__ alignas(16) unsigned short Bs[128 * 64];
  const int tid = threadIdx.x;
  const int w = tid >> 6, l = tid & 63;
  const int l16 = l & 15, lg = l >> 4;
  const int wr = w >> 1, wc = w & 1;
  const long mb = (long)blockIdx.y * 128, nb = (long)blockIdx.x * 128;

  const fx4 fz = {0.f, 0.f, 0.f, 0.f};
  fx4 acc[4][4];
#pragma unroll
  for (int i = 0; i < 4; ++i)
#pragma unroll
    for (int j = 0; j < 4; ++j) acc[i][j] = fz;

  const int sr  = tid >> 3;
  const int sc8 = (tid & 7) * 8;
  const int wbc = sc8 * 2;

  typename RegOf<TA>::type rA[4];
  typename RegOf<TB>::type rB[4];

#pragma unroll
  for (int p = 0; p < 4; ++p) {
    const int row = p * 32 + sr;
    rA[p] = load8(A + (mb + row) * (long)K + sc8);
    rB[p] = load8(B + (nb + row) * (long)K + sc8);
  }

  for (int k0 = 0; k0 < K; k0 += 64) {
    __syncthreads();
#pragma unroll
    for (int p = 0; p < 4; ++p) {
      const int row = p * 32 + sr;
      const int eo = row * 64 + ((wbc ^ ((row & 7) << 4)) >> 1);
      *reinterpret_cast<us8*>(&As[eo]) = toBf(rA[p]);
      *reinterpret_cast<us8*>(&Bs[eo]) = toBf(rB[p]);
    }
    if (k0 + 64 < K) {
#pragma unroll
      for (int p = 0; p < 4; ++p) {
        const int row = p * 32 + sr;
        rA[p] = load8(A + (mb + row) * (long)K + k0 + 64 + sc8);
        rB[p] = load8(B + (nb + row) * (long)K + k0 + 64 + sc8);
      }
    }
    __syncthreads();
#pragma unroll
    for (int kk = 0; kk < 2; ++kk) {
      bx8 a[4], b[4];
#pragma unroll
      for (int mf = 0; mf < 4; ++mf) {
        const int ra = wr * 64 + mf * 16 + l16;
        const int bc = kk * 64 + lg * 16;
        a[mf] = *reinterpret_cast<const bx8*>(&As[ra * 64 + ((bc ^ ((ra & 7) << 4)) >> 1)]);
      }
#pragma unroll
      for (int nf = 0; nf < 4; ++nf) {
        const int rb_ = wc * 64 + nf * 16 + l16;
        const int bc = kk * 64 + lg * 16;
        b[nf] = *reinterpret_cast<const bx8*>(&Bs[rb_ * 64 + ((bc ^ ((rb_ & 7) << 4)) >> 1)]);
      }
#pragma unroll
      for (int mf = 0; mf < 4; ++mf)
#pragma unroll
        for (int nf = 0; nf < 4; ++nf)
          acc[mf][nf] = mfma16(a[mf], b[nf], acc[mf][nf]);
    }
  }

#pragma unroll
  for (int mf = 0; mf < 4; ++mf)
#pragma unroll
    for (int nf = 0; nf < 4; ++nf)
#pragma unroll
      for (int r = 0; r < 4; ++r) {
        const long row = mb + wr * 64 + mf * 16 + lg * 4 + r;
        const long col = nb + wc * 64 + nf * 16 + l16;
        if (F32OUT)
          ((float*)Cp)[row * N + col] = acc[mf][nf][r];
        else
          ((unsigned short*)Cp)[row * N + col] = f2bf(acc[mf][nf][r]);
      }
}

// ---------- flash attention (causal), QBLK=128: 4 waves x 32 q-rows ----------
// R14: K/V LDS fragments read ONCE per step and fed to BOTH q16 halves
// (halves LDS-pipe bytes per FLOP — the R13-counter-diagnosed bottleneck).
// Items: (h, tau=q128-tile, ck) with ntk = 2*tau+2 kv-tiles, 8-tile chunks.
// 640 blocks; each writes O-numerator (128x128 bf16) + per-row (m,l).
//   smem: Ks [64 rows][256B] swz key row&15   @ 0      (16 KiB)
//         Vt [128 rows][128B] swz key row&7   @ 16384  (16 KiB)
//         Ps 4 x [32 rows][128B] swz key row&7 @ 32768 (16 KiB)
__global__ __launch_bounds__(256) void fa_kernel(const unsigned short* __restrict__ qkv,
                                                 unsigned short* __restrict__ Obuf,
                                                 float* __restrict__ ML) {
  __shared__ alignas(16) char smem[49152];

  const int id = blockIdx.x;
  const int h = id & 15, i = id >> 4;   // i in [0,40)
  int tau, ck;
  if (i < 16)      { tau = 15 - (i >> 2); ck = i & 3; }
  else if (i < 28) { const int j = i - 16; tau = 11 - j / 3; ck = j % 3; }
  else if (i < 36) { const int j = i - 28; tau = 7 - (j >> 1); ck = j & 1; }
  else             { tau = 3 - (i - 36); ck = 0; }
  const int ntk = 2 * tau + 2;
  const int t0 = ck * 8;
  const int t1 = min(t0 + 8, ntk);
  const int qb = tau * 128;

  const int tid = threadIdx.x;
  const int w = tid >> 6, l = tid & 63;
  const int l16 = l & 15, lg = l >> 4;
  const fx4 fz = {0.f, 0.f, 0.f, 0.f};

  // staging coordinates (R13-proven)
  const int kr = tid >> 4, ksl = tid & 15;         // K-stage: row kr(+16p), 16B slot ksl
  const int kg = tid & 15, db = tid >> 4;          // V-stage: kv group (4), d block (8)
  const int kc8 = ksl * 8;

  // Q fragments: qf[qh][kc], q row = qb + w*32 + qh*16 + l16
  bx8 qf[2][4];
#pragma unroll
  for (int qh = 0; qh < 2; ++qh) {
    const long qrow = qb + w * 32 + qh * 16 + l16;
    const unsigned short* qp = qkv + qrow * 6144L + h * 128 + lg * 8;
#pragma unroll
    for (int kc = 0; kc < 4; ++kc)
      qf[qh][kc] = *reinterpret_cast<const bx8*>(qp + kc * 32);
  }

  fx4 o_acc[2][8];
#pragma unroll
  for (int qh = 0; qh < 2; ++qh)
#pragma unroll
    for (int i2 = 0; i2 < 8; ++i2) o_acc[qh][i2] = fz;
  float m_r[2][4], l_r[2][4];
#pragma unroll
  for (int qh = 0; qh < 2; ++qh)
#pragma unroll
    for (int r = 0; r < 4; ++r) { m_r[qh][r] = -3e38f; l_r[qh][r] = 0.f; }

  // prologue: load tile t0 into staging regs
  us8 rK[4], rV[4];
  {
    const long kvb = (long)t0 * 64;
#pragma unroll
    for (int p = 0; p < 4; ++p)
      rK[p] = *reinterpret_cast<const us8*>(qkv + (kvb + p * 16 + kr) * 6144L + 2048 + h * 128 + kc8);
#pragma unroll
    for (int p = 0; p < 4; ++p)
      rV[p] = *reinterpret_cast<const us8*>(qkv + (kvb + kg * 4 + p) * 6144L + 4096 + h * 128 + db * 8);
  }

  const float sc2 = 0.1275173831f;  // (1/sqrt(128)) * log2(e)
  char* const psb = smem + 32768 + w * 4096;       // per-wave P buffer: 32 rows x 128B

  for (int t = t0; t < t1; ++t) {
    __syncthreads();  // all waves done with previous LDS tile

    // write staged K (4 x b128), swizzled: slot' = ksl ^ kr
#pragma unroll
    for (int p = 0; p < 4; ++p)
      *reinterpret_cast<us8*>(smem + (p * 16 + kr) * 256 + ((ksl ^ kr) << 4)) = rK[p];
    // write staged V transposed (8 x b64), swizzled
#pragma unroll
    for (int j = 0; j < 8; ++j) {
      us4 vw = {rV[0][j], rV[1][j], rV[2][j], rV[3][j]};
      *reinterpret_cast<us4*>(smem + 16384 + (db * 8 + j) * 128 +
                              (((kg >> 1) ^ j) << 4) + ((kg & 1) << 3)) = vw;
    }

    // issue loads for tile t+1 (land during compute below)
    if (t + 1 < t1) {
      const long kvb = (long)(t + 1) * 64;
#pragma unroll
      for (int p = 0; p < 4; ++p)
        rK[p] = *reinterpret_cast<const us8*>(qkv + (kvb + p * 16 + kr) * 6144L + 2048 + h * 128 + kc8);
#pragma unroll
      for (int p = 0; p < 4; ++p)
        rV[p] = *reinterpret_cast<const us8*>(qkv + (kvb + kg * 4 + p) * 6144L + 4096 + h * 128 + db * 8);
    }
    __syncthreads();  // K and V resident in LDS

    // --- S = Q * K^T : kb read ONCE, feeds both q16 halves ---
    fx4 s[2][4];
#pragma unroll
    for (int qh = 0; qh < 2; ++qh)
#pragma unroll
      for (int nf = 0; nf < 4; ++nf) s[qh][nf] = fz;
#pragma unroll
    for (int kc = 0; kc < 4; ++kc) {
#pragma unroll
      for (int nf = 0; nf < 4; ++nf) {
        const int rl = nf * 16 + l16;
        bx8 kb = *reinterpret_cast<const bx8*>(smem + rl * 256 + (((kc * 4 + lg) ^ l16) << 4));
        s[0][nf] = mfma16(qf[0][kc], kb, s[0][nf]);
        s[1][nf] = mfma16(qf[1][kc], kb, s[1][nf]);
      }
    }

    // --- causal mask (only the last two kv-tiles can cross the diagonal) ---
    if (t >= ntk - 2) {
#pragma unroll
      for (int qh = 0; qh < 2; ++qh)
#pragma unroll
        for (int nf = 0; nf < 4; ++nf) {
          const int kv_abs = t * 64 + nf * 16 + l16;
#pragma unroll
          for (int r = 0; r < 4; ++r) {
            const int q_abs = qb + w * 32 + qh * 16 + lg * 4 + r;
            if (kv_abs > q_abs) s[qh][nf][r] = -3e38f;
          }
        }
    }

    // --- online softmax with defer-rescale (T13), per q-half ---
    float rm_[2][4];
    bool st = true;
#pragma unroll
    for (int qh = 0; qh < 2; ++qh)
#pragma unroll
      for (int r = 0; r < 4; ++r) {
        float rm = fmaxf(fmaxf(s[qh][0][r], s[qh][1][r]), fmaxf(s[qh][2][r], s[qh][3][r]));
        rm_[qh][r] = rowmax16(rm);
        st = st && (rm_[qh][r] - m_r[qh][r] <= 62.7f);   // *sc2 ~= 8 -> P <= 2^8
      }
    float pv[2][4][4];
    if (__all(st ? 1 : 0)) {
#pragma unroll
      for (int qh = 0; qh < 2; ++qh)
#pragma unroll
        for (int r = 0; r < 4; ++r) {
          float rs = 0.f;
#pragma unroll
          for (int nf = 0; nf < 4; ++nf) {
            const float p = exp2f((s[qh][nf][r] - m_r[qh][r]) * sc2);
            pv[qh][nf][r] = p;
            rs += p;
          }
          l_r[qh][r] += rowsum16(rs);
        }
    } else {
#pragma unroll
      for (int qh = 0; qh < 2; ++qh)
#pragma unroll
        for (int r = 0; r < 4; ++r) {
          const float mn = fmaxf(m_r[qh][r], rm_[qh][r]);
          const float fac = exp2f((m_r[qh][r] - mn) * sc2);
          m_r[qh][r] = mn;
          float rs = 0.f;
#pragma unroll
          for (int nf = 0; nf < 4; ++nf) {
            const float p = exp2f((s[qh][nf][r] - mn) * sc2);
            pv[qh][nf][r] = p;
            rs += p;
          }
          l_r[qh][r] = l_r[qh][r] * fac + rowsum16(rs);
#pragma unroll
          for (int nf = 0; nf < 8; ++nf) o_acc[qh][nf][r] *= fac;
        }
    }

    // --- P -> per-wave LDS (swizzled, 32 rows) -> A-fragments ---
#pragma unroll
    for (int qh = 0; qh < 2; ++qh)
#pragma unroll
      for (int nf = 0; nf < 4; ++nf)
#pragma unroll
        for (int r = 0; r < 4; ++r) {
          const int ro = qh * 16 + lg * 4 + r;
          *reinterpret_cast<unsigned short*>(
              psb + ro * 128 + (((nf * 2 + (l16 >> 3)) ^ (ro & 7)) << 4) + ((l16 & 7) << 1)) =
              __builtin_bit_cast(unsigned short, (__bf16)pv[qh][nf][r]);
        }

    bx8 pa[2][2];
#pragma unroll
    for (int qh = 0; qh < 2; ++qh)
#pragma unroll
      for (int kc = 0; kc < 2; ++kc)
        pa[qh][kc] = *reinterpret_cast<const bx8*>(
            psb + (qh * 16 + l16) * 128 + (((kc * 4 + lg) ^ (l16 & 7)) << 4));

    // --- O += P * V : vb read ONCE, feeds both q16 halves ---
#pragma unroll
    for (int nf = 0; nf < 8; ++nf) {
#pragma unroll
      for (int kc = 0; kc < 2; ++kc) {
        bx8 vb = *reinterpret_cast<const bx8*>(smem + 16384 + (nf * 16 + l16) * 128 +
                                               (((kc * 4 + lg) ^ (l16 & 7)) << 4));
        o_acc[0][nf] = mfma16(pa[0][kc], vb, o_acc[0][nf]);
        o_acc[1][nf] = mfma16(pa[1][kc], vb, o_acc[1][nf]);
      }
    }
  }

  // write O-numerator (bf16, 128x128) + per-row (m, l) partials
  unsigned short* ob = Obuf + (long)id * 16384;
#pragma unroll
  for (int qh = 0; qh < 2; ++qh)
#pragma unroll
    for (int nf = 0; nf < 8; ++nf)
#pragma unroll
      for (int r = 0; r < 4; ++r) {
        const int row = w * 32 + qh * 16 + lg * 4 + r;
        ob[row * 128 + nf * 16 + l16] = f2bf(o_acc[qh][nf][r]);
      }
  if (l16 == 0) {
#pragma unroll
    for (int qh = 0; qh < 2; ++qh)
#pragma unroll
      for (int r = 0; r < 4; ++r) {
        const int row = w * 32 + qh * 16 + lg * 4 + r;
        ML[((long)id * 128 + row) * 2 + 0] = m_r[qh][r];
        ML[((long)id * 128 + row) * 2 + 1] = l_r[qh][r];
      }
  }
}

// ---------- combine <=4 chunk partials into attnb ----------
// grid 512: p -> th = p>>1 (tau = th>>4, h = th&15), half = p&1 (64 rows each).
__global__ __launch_bounds__(256) void fa_combine(const unsigned short* __restrict__ Obuf,
                                                  const float* __restrict__ ML,
                                                  unsigned short* __restrict__ out) {
  const int p = blockIdx.x;
  const int th = p >> 1, half = p & 1;
  const int tau = th >> 4, h = th & 15;
  const int nc = (tau >= 12) ? 4 : (tau >= 8) ? 3 : (tau >= 4) ? 2 : 1;
  const int tid = threadIdx.x;
  const int row = half * 64 + (tid >> 2);   // 0..127
  const int c0 = (tid & 3) * 32;
  const float sc2 = 0.1275173831f;

  int ids[4];
#pragma unroll
  for (int k = 0; k < 4; ++k) {
    int ib;
    if (tau >= 12)     ib = (15 - tau) * 4 + k;
    else if (tau >= 8) ib = 16 + (11 - tau) * 3 + k;
    else if (tau >= 4) ib = 28 + (7 - tau) * 2 + k;
    else               ib = 36 + (3 - tau);
    ids[k] = ib * 16 + h;
  }

  float mk[4], lk[4];
  float m = -3e38f;
#pragma unroll
  for (int k = 0; k < 4; ++k)
    if (k < nc) {
      mk[k] = ML[((long)ids[k] * 128 + row) * 2 + 0];
      lk[k] = ML[((long)ids[k] * 128 + row) * 2 + 1];
      m = fmaxf(m, mk[k]);
    }
  float fk[4], denom = 0.f;
#pragma unroll
  for (int k = 0; k < 4; ++k)
    if (k < nc) {
      fk[k] = exp2f((mk[k] - m) * sc2);
      denom += lk[k] * fk[k];
    }
  const float inv = 1.0f / denom;

  float acc[32];
#pragma unroll
  for (int j = 0; j < 32; ++j) acc[j] = 0.f;
#pragma unroll
  for (int k = 0; k < 4; ++k)
    if (k < nc) {
      const unsigned short* ob = Obuf + (long)ids[k] * 16384 + row * 128 + c0;
      const float f = fk[k];
#pragma unroll
      for (int jj = 0; jj < 4; ++jj) {
        us8 a = *reinterpret_cast<const us8*>(ob + jj * 8);
#pragma unroll
        for (int j2 = 0; j2 < 8; ++j2) acc[jj * 8 + j2] += bf2f(a[j2]) * f;
      }
    }

  unsigned short* dst = out + (long)(tau * 128 + row) * 2048 + h * 128 + c0;
#pragma unroll
  for (int jj = 0; jj < 4; ++jj) {
    ushort4 o0, o1;
    o0.x = f2bf(acc[jj * 8 + 0] * inv);
    o0.y = f2bf(acc[jj * 8 + 1] * inv);
    o0.z = f2bf(acc[jj * 8 + 2] * inv);
    o0.w = f2bf(acc[jj * 8 + 3] * inv);
    o1.x = f2bf(acc[jj * 8 + 4] * inv);
    o1.y = f2bf(acc[jj * 8 + 5] * inv);
    o1.z = f2bf(acc[jj * 8 + 6] * inv);
    o1.w = f2bf(acc[jj * 8 + 7] * inv);
    *reinterpret_cast<ushort4*>(dst + jj * 8) = o0;
    *reinterpret_cast<ushort4*>(dst + jj * 8 + 4) = o1;
  }
}

// ---------- launch ----------
// Interface (confirmed R4): inputs fp32, output fp32.
// Workspace plan (peak 56 MiB):
//   wab   [0, 24 MiB)     bf16 W_attn (dead after GEMM1)
//   qkvb  [24, 48 MiB)    bf16 qkv
//   xb    [48, 56 MiB)    bf16 x (dead after GEMM1)
//   -- after GEMM1, overlaying dead regions:
//   Obuf  [0, 20 MiB)     640 x 128x128 bf16 partial O numerators
//   ML    [20, 20.625)    640 x 128 x (m,l) fp32
//   attnb [48, 56 MiB)    bf16 attn out (overlays dead xb)
extern "C" void kernel_launch(void* const* d_in, const int* in_sizes, int n_in,
                              void* d_out, int out_size, void* d_ws, size_t ws_size,
                              hipStream_t stream) {
  const float* x  = (const float*)d_in[0];   // (2048, 2048) fp32
  const float* Wa = (const float*)d_in[1];   // (6144, 2048) fp32
  const float* Wp = (const float*)d_in[2];   // (2048, 2048) fp32
  float* out = (float*)d_out;                // (2048, 2048) fp32
  char* ws = (char*)d_ws;

  unsigned short* wab   = (unsigned short*)(ws);                 // 24 MiB
  unsigned short* qkvb  = (unsigned short*)(ws + (24ull << 20)); // 24 MiB
  unsigned short* xb    = (unsigned short*)(ws + (48ull << 20)); //  8 MiB
  unsigned short* Obuf  = (unsigned short*)(ws);                 // 20 MiB (after GEMM1)
  float*          ML    = (float*)(ws + (20ull << 20));          // 640 KiB (after GEMM1)
  unsigned short* attnb = (unsigned short*)(ws + (48ull << 20)); //  8 MiB (after GEMM1)

  f2b_kernel<<<4096, 256, 0, stream>>>(x, xb, 2048 * 2048);
  f2b_kernel<<<12288, 256, 0, stream>>>(Wa, wab, 6144 * 2048);

  // qkv = x @ W_attn^T : M=2048, N=6144, K=2048 — deep-pipelined 256^2 kernel
  gemm256<<<dim3(24, 8), 512, 0, stream>>>(xb, wab, qkvb, 2048, 6144, 2048);

  // causal flash attention: 640 q128-tile chunk items (heavy first)
  fa_kernel<<<640, 256, 0, stream>>>(qkvb, Obuf, ML);

  // merge 1..4 chunk partials per (tau, h)
  fa_combine<<<512, 256, 0, stream>>>(Obuf, ML, attnb);

  // out = attn @ W_proj^T : M=2048, N=2048, K=2048 (A bf16, B fp32 fold, fp32 out)
  gemm_bt<unsigned short, float, true><<<dim3(16, 16), 256, 0, stream>>>(attnb, Wp, (void*)out, 2048, 2048, 2048);
}

// Round 15
// 180.007 us; speedup vs baseline: 1.1331x; 1.1331x over previous
//
#include <hip/hip_runtime.h>
#include <cstdint>

// ---------- types ----------
using bx8 = __attribute__((ext_vector_type(8))) __bf16;   // MFMA A/B fragment (8 bf16)
using us8 = __attribute__((ext_vector_type(8))) unsigned short;
using us4 = __attribute__((ext_vector_type(4))) unsigned short;
using fl8 = __attribute__((ext_vector_type(8))) float;
using fx4 = __attribute__((ext_vector_type(4))) float;    // MFMA C/D fragment

static __device__ inline unsigned short f2bf(float f) {
  unsigned u = __builtin_bit_cast(unsigned, f);
  unsigned r = 0x7FFFu + ((u >> 16) & 1u);   // round-to-nearest-even
  return (unsigned short)((u + r) >> 16);
}
static __device__ inline float bf2f(unsigned short s) {
  return __builtin_bit_cast(float, (unsigned)s << 16);
}

static __device__ inline fx4 mfma16(bx8 a, bx8 b, fx4 c) {
  return __builtin_amdgcn_mfma_f32_16x16x32_bf16(a, b, c, 0, 0, 0);
}

// async global->LDS, 16B/lane; dest = wave-uniform base + lane*16 (R9-proven w/ drain)
static __device__ inline void gload16(const void* g, void* lds) {
  __builtin_amdgcn_global_load_lds(
      (const __attribute__((address_space(1))) void*)g,
      (__attribute__((address_space(3))) void*)lds,
      16, 0, 0);
}
#define VMCNT(n) asm volatile("s_waitcnt vmcnt(" #n ")" ::: "memory")
// raw barrier (does NOT drain vmcnt, unlike __syncthreads) + compiler fences
static __device__ inline void wave_barrier() {
  __builtin_amdgcn_sched_barrier(0);
  __builtin_amdgcn_s_barrier();
  __builtin_amdgcn_sched_barrier(0);
}
// LDS-only barrier: drains lgkmcnt (cross-wave LDS visibility) but NOT vmcnt —
// register-destination global prefetch loads stay in flight across it.
// (__syncthreads drains vmcnt(0) too: that was fa's hidden ~4k cy/step stall.)
static __device__ inline void lds_barrier() {
  __builtin_amdgcn_sched_barrier(0);
  asm volatile("s_waitcnt lgkmcnt(0)" ::: "memory");
  __builtin_amdgcn_s_barrier();
  __builtin_amdgcn_sched_barrier(0);
}

// DPP row_ror:k (VALU-latency cross-lane)
#define DPP_ROR(x, k) __builtin_bit_cast(float, __builtin_amdgcn_update_dpp( \
    __builtin_bit_cast(int, x), __builtin_bit_cast(int, x), 0x120 | (k), 0xF, 0xF, false))

static __device__ inline float rowmax16(float v) {
  v = fmaxf(v, DPP_ROR(v, 1));
  v = fmaxf(v, DPP_ROR(v, 2));
  v = fmaxf(v, DPP_ROR(v, 4));
  v = fmaxf(v, DPP_ROR(v, 8));
  return v;
}
static __device__ inline float rowsum16(float v) {
  v += DPP_ROR(v, 1);
  v += DPP_ROR(v, 2);
  v += DPP_ROR(v, 4);
  v += DPP_ROR(v, 8);
  return v;
}

// ---------- fp32 -> bf16 convert (R4-proven) ----------
__global__ __launch_bounds__(256) void f2b_kernel(const float* __restrict__ in,
                                                  unsigned short* __restrict__ out,
                                                  int n) {
  int i = (blockIdx.x * 256 + threadIdx.x) * 4;
  if (i >= n) return;
  float4 v = *reinterpret_cast<const float4*>(in + i);
  ushort4 o;
  o.x = f2bf(v.x); o.y = f2bf(v.y); o.z = f2bf(v.z); o.w = f2bf(v.w);
  *reinterpret_cast<ushort4*>(out + i) = o;
}

// ================= GEMM1: 256x256 tile, BK=32, depth-3 counted-vmcnt pipeline (R10-proven) =================
__global__ __launch_bounds__(512, 2) void gemm256(const unsigned short* __restrict__ A,
                                                  const unsigned short* __restrict__ B,
                                                  unsigned short* __restrict__ C,
                                                  int M, int N, int K) {
  __shared__ unsigned short lds[4][2][256 * 32];   // [buf][A/B][row*32 + col]

  const int tid = threadIdx.x;
  const int w = tid >> 6, l = tid & 63;
  const int l16 = l & 15, lg = l >> 4;
  const int wr = w >> 2, wc = w & 3;
  const long mb = (long)blockIdx.y * 256, nb = (long)blockIdx.x * 256;

  const int lr = l >> 2;
  const int sw = (((l & 3) ^ (lr & 3)) * 8);       // pre-swizzled col (elements)
  const unsigned short* Ag = A + (mb + w * 32 + lr) * (long)K + sw;
  const unsigned short* Bg = B + (nb + w * 32 + lr) * (long)K + sw;

  const int rdcol = ((lg ^ (l16 & 3)) * 16);

  const fx4 fz = {0.f, 0.f, 0.f, 0.f};
  fx4 acc[8][4];
#pragma unroll
  for (int i = 0; i < 8; ++i)
#pragma unroll
    for (int j = 0; j < 4; ++j) acc[i][j] = fz;

  const int nt = K >> 5;   // K/32 tiles

  auto stage = [&](int tp) {
    const int db = tp & 3;
    const unsigned short* as = Ag + tp * 32;
    const unsigned short* bs = Bg + tp * 32;
    char* al = (char*)&lds[db][0][0] + w * 32 * 64;
    char* bl = (char*)&lds[db][1][0] + w * 32 * 64;
    gload16(as, al);
    gload16(as + 16 * (long)K, al + 1024);
    gload16(bs, bl);
    gload16(bs + 16 * (long)K, bl + 1024);
  };

  auto compute = [&](int bt) {
    const char* Ab = (const char*)&lds[bt][0][0] + (wr * 128 + l16) * 64 + rdcol;
    const char* Bb = (const char*)&lds[bt][1][0] + (wc * 64 + l16) * 64 + rdcol;
    bx8 bf[4];
#pragma unroll
    for (int nf = 0; nf < 4; ++nf)
      bf[nf] = *reinterpret_cast<const bx8*>(Bb + nf * 1024);
    __builtin_amdgcn_s_setprio(1);
#pragma unroll
    for (int mf = 0; mf < 8; ++mf) {
      bx8 av = *reinterpret_cast<const bx8*>(Ab + mf * 1024);
#pragma unroll
      for (int nf = 0; nf < 4; ++nf)
        acc[mf][nf] = mfma16(av, bf[nf], acc[mf][nf]);
    }
    __builtin_amdgcn_s_setprio(0);
  };

  stage(0); stage(1); stage(2);
  VMCNT(8);
  wave_barrier();

  int t = 0;
  for (; t < nt - 3; ++t) {
    stage(t + 3);
    compute(t & 3);
    VMCNT(8);
    wave_barrier();
  }
  compute(t & 3); VMCNT(4); wave_barrier(); ++t;
  compute(t & 3); VMCNT(0); wave_barrier(); ++t;
  compute(t & 3);

#pragma unroll
  for (int mf = 0; mf < 8; ++mf)
#pragma unroll
    for (int nf = 0; nf < 4; ++nf)
#pragma unroll
      for (int r = 0; r < 4; ++r) {
        const long row = mb + wr * 128 + mf * 16 + lg * 4 + r;
        const long col = nb + wc * 64 + nf * 16 + l16;
        C[row * N + col] = f2bf(acc[mf][nf][r]);
      }
}

// ---------- staging-reg type per operand dtype (R8-proven fold GEMM) ----------
template <typename T> struct RegOf { using type = us8; };
template <> struct RegOf<float>  { using type = fl8; };

template <typename T>
static __device__ inline typename RegOf<T>::type load8(const T* p) {
  return *reinterpret_cast<const typename RegOf<T>::type*>(p);
}
static __device__ inline us8 toBf(us8 v) { return v; }
static __device__ inline us8 toBf(fl8 f) {
  us8 o;
#pragma unroll
  for (int j = 0; j < 8; ++j) {
    __bf16 b = (__bf16)f[j];
    o[j] = __builtin_bit_cast(unsigned short, b);
  }
  return o;
}

// ---------- GEMM2: R8-proven 128x128 reg-staged fold kernel + vmcnt-free barriers ----------
template <typename TA, typename TB, bool F32OUT>
__global__ __launch_bounds__(256) void gemm_bt(const TA* __restrict__ A,
                                               const TB* __restrict__ B,
                                               void* __restrict__ Cp,
                                               int M, int N, int K) {
  __shared__ alignas(16) unsigned short As[128 * 64];
  __shared__ alignas(16) unsigned short Bs[128 * 64];
  const int tid = threadIdx.x;
  const int w = tid >> 6, l = tid & 63;
  const int l16 = l & 15, lg = l >> 4;
  const int wr = w >> 1, wc = w & 1;
  const long mb = (long)blockIdx.y * 128, nb = (long)blockIdx.x * 128;

  const fx4 fz = {0.f, 0.f, 0.f, 0.f};
  fx4 acc[4][4];
#pragma unroll
  for (int i = 0; i < 4; ++i)
#pragma unroll
    for (int j = 0; j < 4; ++j) acc[i][j] = fz;

  const int sr  = tid >> 3;
  const int sc8 = (tid & 7) * 8;
  const int wbc = sc8 * 2;

  typename RegOf<TA>::type rA[4];
  typename RegOf<TB>::type rB[4];

#pragma unroll
  for (int p = 0; p < 4; ++p) {
    const int row = p * 32 + sr;
    rA[p] = load8(A + (mb + row) * (long)K + sc8);
    rB[p] = load8(B + (nb + row) * (long)K + sc8);
  }

  for (int k0 = 0; k0 < K; k0 += 64) {
    lds_barrier();   // prior iter's LDS reads done (no vmcnt drain)
#pragma unroll
    for (int p = 0; p < 4; ++p) {
      const int row = p * 32 + sr;
      const int eo = row * 64 + ((wbc ^ ((row & 7) << 4)) >> 1);
      *reinterpret_cast<us8*>(&As[eo]) = toBf(rA[p]);
      *reinterpret_cast<us8*>(&Bs[eo]) = toBf(rB[p]);
    }
    if (k0 + 64 < K) {
#pragma unroll
      for (int p = 0; p < 4; ++p) {
        const int row = p * 32 + sr;
        rA[p] = load8(A + (mb + row) * (long)K + k0 + 64 + sc8);
        rB[p] = load8(B + (nb + row) * (long)K + k0 + 64 + sc8);
      }
    }
    lds_barrier();   // tiles resident; prefetch loads stay in flight
#pragma unroll
    for (int kk = 0; kk < 2; ++kk) {
      bx8 a[4], b[4];
#pragma unroll
      for (int mf = 0; mf < 4; ++mf) {
        const int ra = wr * 64 + mf * 16 + l16;
        const int bc = kk * 64 + lg * 16;
        a[mf] = *reinterpret_cast<const bx8*>(&As[ra * 64 + ((bc ^ ((ra & 7) << 4)) >> 1)]);
      }
#pragma unroll
      for (int nf = 0; nf < 4; ++nf) {
        const int rb_ = wc * 64 + nf * 16 + l16;
        const int bc = kk * 64 + lg * 16;
        b[nf] = *reinterpret_cast<const bx8*>(&Bs[rb_ * 64 + ((bc ^ ((rb_ & 7) << 4)) >> 1)]);
      }
#pragma unroll
      for (int mf = 0; mf < 4; ++mf)
#pragma unroll
        for (int nf = 0; nf < 4; ++nf)
          acc[mf][nf] = mfma16(a[mf], b[nf], acc[mf][nf]);
    }
  }

#pragma unroll
  for (int mf = 0; mf < 4; ++mf)
#pragma unroll
    for (int nf = 0; nf < 4; ++nf)
#pragma unroll
      for (int r = 0; r < 4; ++r) {
        const long row = mb + wr * 64 + mf * 16 + lg * 4 + r;
        const long col = nb + wc * 64 + nf * 16 + l16;
        if (F32OUT)
          ((float*)Cp)[row * N + col] = acc[mf][nf][r];
        else
          ((unsigned short*)Cp)[row * N + col] = f2bf(acc[mf][nf][r]);
      }
}

// ---------- flash attention (causal), uniform 8-tile chunks, all-partial ----------
// R15 = R13-proven body (64 q-rows, 40 KiB swizzled LDS, 1280 items) with ONE
// change: both __syncthreads -> lds_barrier (no vmcnt drain). The t+1 global
// prefetch loads now genuinely overlap compute(t) instead of being drained
// at the barrier (the diagnosed ~4k cy/step stall).
//   smem: Ks [64 rows][256B] swz key row&15   @ 0      (16 KiB)
//         Vt [128 rows][128B] swz key row&7   @ 16384  (16 KiB)
//         Ps 4 x [16 rows][128B] swz key row&7 @ 32768 (8 KiB)
__global__ __launch_bounds__(256) void fa_kernel(const unsigned short* __restrict__ qkv,
                                                 unsigned short* __restrict__ Obuf,
                                                 float* __restrict__ ML) {
  __shared__ alignas(16) char smem[40960];

  const int id = blockIdx.x;
  const int h = id & 15, i = id >> 4;
  int qt, ck;
  if (i < 32)      { qt = 31 - (i >> 2); ck = i & 3; }
  else if (i < 56) { const int j = i - 32; qt = 23 - j / 3; ck = j % 3; }
  else if (i < 72) { const int j = i - 56; qt = 15 - (j >> 1); ck = j & 1; }
  else             { qt = 7 - (i - 72); ck = 0; }
  const int t0 = ck * 8;
  const int t1 = min(t0 + 8, qt + 1);
  const int qb = qt * 64;

  const int tid = threadIdx.x;
  const int w = tid >> 6, l = tid & 63;
  const int l16 = l & 15, lg = l >> 4;
  const fx4 fz = {0.f, 0.f, 0.f, 0.f};

  // staging coordinates
  const int kr = tid >> 4, ksl = tid & 15;         // K-stage: row kr(+16p), 16B slot ksl
  const int kg = tid & 15, db = tid >> 4;          // V-stage: kv group (4), d block (8)
  const int kc8 = ksl * 8;                         // K-stage global col (elements)

  // Q fragments in registers: A-frag row = l&15, k = (l>>4)*8 + j
  bx8 qf[4];
  {
    const long qrow = qb + w * 16 + l16;
    const unsigned short* qp = qkv + qrow * 6144L + h * 128 + lg * 8;
#pragma unroll
    for (int kc = 0; kc < 4; ++kc)
      qf[kc] = *reinterpret_cast<const bx8*>(qp + kc * 32);
  }

  fx4 o_acc[8];
#pragma unroll
  for (int i2 = 0; i2 < 8; ++i2) o_acc[i2] = fz;
  float m_r[4] = {-3e38f, -3e38f, -3e38f, -3e38f};
  float l_r[4] = {0.f, 0.f, 0.f, 0.f};

  // prologue: load tile t0 into staging regs
  us8 rK[4], rV[4];
  {
    const long kvb = (long)t0 * 64;
#pragma unroll
    for (int p = 0; p < 4; ++p)
      rK[p] = *reinterpret_cast<const us8*>(qkv + (kvb + p * 16 + kr) * 6144L + 2048 + h * 128 + kc8);
#pragma unroll
    for (int p = 0; p < 4; ++p)
      rV[p] = *reinterpret_cast<const us8*>(qkv + (kvb + kg * 4 + p) * 6144L + 4096 + h * 128 + db * 8);
  }

  const float sc2 = 0.1275173831f;  // (1/sqrt(128)) * log2(e)
  char* const psb = smem + 32768 + w * 2048;       // per-wave P buffer

  for (int t = t0; t < t1; ++t) {
    lds_barrier();   // all waves done reading previous LDS tile (no vmcnt drain)

    // write staged K (4 x b128), swizzled: slot' = ksl ^ kr
#pragma unroll
    for (int p = 0; p < 4; ++p)
      *reinterpret_cast<us8*>(smem + (p * 16 + kr) * 256 + ((ksl ^ kr) << 4)) = rK[p];
    // write staged V transposed (8 x b64), swizzled
#pragma unroll
    for (int j = 0; j < 8; ++j) {
      us4 vw = {rV[0][j], rV[1][j], rV[2][j], rV[3][j]};
      *reinterpret_cast<us4*>(smem + 16384 + (db * 8 + j) * 128 +
                              (((kg >> 1) ^ j) << 4) + ((kg & 1) << 3)) = vw;
    }

    // issue loads for tile t+1 — they stay in flight across the barrier below
    if (t + 1 < t1) {
      const long kvb = (long)(t + 1) * 64;
#pragma unroll
      for (int p = 0; p < 4; ++p)
        rK[p] = *reinterpret_cast<const us8*>(qkv + (kvb + p * 16 + kr) * 6144L + 2048 + h * 128 + kc8);
#pragma unroll
      for (int p = 0; p < 4; ++p)
        rV[p] = *reinterpret_cast<const us8*>(qkv + (kvb + kg * 4 + p) * 6144L + 4096 + h * 128 + db * 8);
    }
    lds_barrier();   // K and V visible to all waves; prefetch NOT drained

    // --- S = Q * K^T  (16 q x 64 kv per wave) ---
    fx4 s[4];
#pragma unroll
    for (int nf = 0; nf < 4; ++nf) s[nf] = fz;
#pragma unroll
    for (int kc = 0; kc < 4; ++kc) {
#pragma unroll
      for (int nf = 0; nf < 4; ++nf) {
        const int rl = nf * 16 + l16;
        bx8 kb = *reinterpret_cast<const bx8*>(smem + rl * 256 + (((kc * 4 + lg) ^ l16) << 4));
        s[nf] = mfma16(qf[kc], kb, s[nf]);
      }
    }

    // --- causal mask (possible only on tile t == qt) ---
    if (t == qt) {
#pragma unroll
      for (int nf = 0; nf < 4; ++nf) {
        const int kv_abs = t * 64 + nf * 16 + l16;
#pragma unroll
        for (int r = 0; r < 4; ++r) {
          const int q_abs = qb + w * 16 + lg * 4 + r;
          if (kv_abs > q_abs) s[nf][r] = -3e38f;
        }
      }
    }

    // --- online softmax with defer-rescale (T13) ---
    float rm_[4];
    bool st = true;
#pragma unroll
    for (int r = 0; r < 4; ++r) {
      float rm = fmaxf(fmaxf(s[0][r], s[1][r]), fmaxf(s[2][r], s[3][r]));
      rm_[r] = rowmax16(rm);
      st = st && (rm_[r] - m_r[r] <= 62.7f);   // 62.7*sc2 ~= 8 -> P <= 2^8
    }
    float pv[4][4];
    if (__all(st ? 1 : 0)) {
#pragma unroll
      for (int r = 0; r < 4; ++r) {
        float rs = 0.f;
#pragma unroll
        for (int nf = 0; nf < 4; ++nf) {
          const float p = exp2f((s[nf][r] - m_r[r]) * sc2);
          pv[nf][r] = p;
          rs += p;
        }
        l_r[r] += rowsum16(rs);
      }
    } else {
#pragma unroll
      for (int r = 0; r < 4; ++r) {
        const float mn = fmaxf(m_r[r], rm_[r]);
        const float fac = exp2f((m_r[r] - mn) * sc2);
        m_r[r] = mn;
        float rs = 0.f;
#pragma unroll
        for (int nf = 0; nf < 4; ++nf) {
          const float p = exp2f((s[nf][r] - mn) * sc2);
          pv[nf][r] = p;
          rs += p;
        }
        l_r[r] = l_r[r] * fac + rowsum16(rs);
#pragma unroll
        for (int nf = 0; nf < 8; ++nf) o_acc[nf][r] *= fac;
      }
    }

    // --- P -> per-wave LDS (swizzled) -> A-fragments (same-wave, lgkm-ordered) ---
#pragma unroll
    for (int nf = 0; nf < 4; ++nf)
#pragma unroll
      for (int r = 0; r < 4; ++r) {
        const int ro = lg * 4 + r;
        *reinterpret_cast<unsigned short*>(
            psb + ro * 128 + (((nf * 2 + (l16 >> 3)) ^ (ro & 7)) << 4) + ((l16 & 7) << 1)) =
            __builtin_bit_cast(unsigned short, (__bf16)pv[nf][r]);
      }

    bx8 pa[2];
#pragma unroll
    for (int kc = 0; kc < 2; ++kc)
      pa[kc] = *reinterpret_cast<const bx8*>(psb + l16 * 128 + (((kc * 4 + lg) ^ (l16 & 7)) << 4));

    // --- O += P * V ---
#pragma unroll
    for (int nf = 0; nf < 8; ++nf) {
#pragma unroll
      for (int kc = 0; kc < 2; ++kc) {
        bx8 vb = *reinterpret_cast<const bx8*>(smem + 16384 + (nf * 16 + l16) * 128 +
                                               (((kc * 4 + lg) ^ (l16 & 7)) << 4));
        o_acc[nf] = mfma16(pa[kc], vb, o_acc[nf]);
      }
    }
  }

  // write O-numerator (bf16) + per-row (m, l) partials
  unsigned short* ob = Obuf + (long)id * 8192;
#pragma unroll
  for (int nf = 0; nf < 8; ++nf)
#pragma unroll
    for (int r = 0; r < 4; ++r) {
      const int row = w * 16 + lg * 4 + r;
      ob[row * 128 + nf * 16 + l16] = f2bf(o_acc[nf][r]);
    }
  if (l16 == 0) {
#pragma unroll
    for (int r = 0; r < 4; ++r) {
      const int row = w * 16 + lg * 4 + r;
      ML[((long)id * 64 + row) * 2 + 0] = m_r[r];
      ML[((long)id * 64 + row) * 2 + 1] = l_r[r];
    }
  }
}

// ---------- combine <=4 chunk partials into attnb (R11-proven) ----------
__global__ __launch_bounds__(256) void fa_combine(const unsigned short* __restrict__ Obuf,
                                                  const float* __restrict__ ML,
                                                  unsigned short* __restrict__ out) {
  const int p = blockIdx.x;
  const int qt = p >> 4, h = p & 15;
  const int nc = (qt + 8) >> 3;
  const int tid = threadIdx.x;
  const int row = tid >> 2;
  const int c0 = (tid & 3) * 32;
  const float sc2 = 0.1275173831f;

  int ids[4];
#pragma unroll
  for (int k = 0; k < 4; ++k) {
    int ib;
    if (qt >= 24)      ib = (31 - qt) * 4 + k;
    else if (qt >= 16) ib = 32 + (23 - qt) * 3 + k;
    else if (qt >= 8)  ib = 56 + (15 - qt) * 2 + k;
    else               ib = 72 + (7 - qt);
    ids[k] = ib * 16 + h;
  }

  float mk[4], lk[4];
  float m = -3e38f;
#pragma unroll
  for (int k = 0; k < 4; ++k)
    if (k < nc) {
      mk[k] = ML[((long)ids[k] * 64 + row) * 2 + 0];
      lk[k] = ML[((long)ids[k] * 64 + row) * 2 + 1];
      m = fmaxf(m, mk[k]);
    }
  float fk[4], denom = 0.f;
#pragma unroll
  for (int k = 0; k < 4; ++k)
    if (k < nc) {
      fk[k] = exp2f((mk[k] - m) * sc2);
      denom += lk[k] * fk[k];
    }
  const float inv = 1.0f / denom;

  float acc[32];
#pragma unroll
  for (int j = 0; j < 32; ++j) acc[j] = 0.f;
#pragma unroll
  for (int k = 0; k < 4; ++k)
    if (k < nc) {
      const unsigned short* ob = Obuf + (long)ids[k] * 8192 + row * 128 + c0;
      const float f = fk[k];
#pragma unroll
      for (int jj = 0; jj < 4; ++jj) {
        us8 a = *reinterpret_cast<const us8*>(ob + jj * 8);
#pragma unroll
        for (int j2 = 0; j2 < 8; ++j2) acc[jj * 8 + j2] += bf2f(a[j2]) * f;
      }
    }

  unsigned short* dst = out + (long)(qt * 64 + row) * 2048 + h * 128 + c0;
#pragma unroll
  for (int jj = 0; jj < 4; ++jj) {
    ushort4 o0, o1;
    o0.x = f2bf(acc[jj * 8 + 0] * inv);
    o0.y = f2bf(acc[jj * 8 + 1] * inv);
    o0.z = f2bf(acc[jj * 8 + 2] * inv);
    o0.w = f2bf(acc[jj * 8 + 3] * inv);
    o1.x = f2bf(acc[jj * 8 + 4] * inv);
    o1.y = f2bf(acc[jj * 8 + 5] * inv);
    o1.z = f2bf(acc[jj * 8 + 6] * inv);
    o1.w = f2bf(acc[jj * 8 + 7] * inv);
    *reinterpret_cast<ushort4*>(dst + jj * 8) = o0;
    *reinterpret_cast<ushort4*>(dst + jj * 8 + 4) = o1;
  }
}

// ---------- launch ----------
// Interface (confirmed R4): inputs fp32, output fp32.
// Workspace plan (peak 56 MiB):
//   wab   [0, 24 MiB)     bf16 W_attn (dead after GEMM1)
//   qkvb  [24, 48 MiB)    bf16 qkv
//   xb    [48, 56 MiB)    bf16 x (dead after GEMM1)
//   -- after GEMM1, overlaying dead regions:
//   Obuf  [0, 20 MiB)     1280 x 64x128 bf16 partial O numerators
//   ML    [20, 20.625)    1280 x 64 x (m,l) fp32
//   attnb [48, 56 MiB)    bf16 attn out (overlays dead xb)
extern "C" void kernel_launch(void* const* d_in, const int* in_sizes, int n_in,
                              void* d_out, int out_size, void* d_ws, size_t ws_size,
                              hipStream_t stream) {
  const float* x  = (const float*)d_in[0];   // (2048, 2048) fp32
  const float* Wa = (const float*)d_in[1];   // (6144, 2048) fp32
  const float* Wp = (const float*)d_in[2];   // (2048, 2048) fp32
  float* out = (float*)d_out;                // (2048, 2048) fp32
  char* ws = (char*)d_ws;

  unsigned short* wab   = (unsigned short*)(ws);                 // 24 MiB
  unsigned short* qkvb  = (unsigned short*)(ws + (24ull << 20)); // 24 MiB
  unsigned short* xb    = (unsigned short*)(ws + (48ull << 20)); //  8 MiB
  unsigned short* Obuf  = (unsigned short*)(ws);                 // 20 MiB (after GEMM1)
  float*          ML    = (float*)(ws + (20ull << 20));          // 640 KiB (after GEMM1)
  unsigned short* attnb = (unsigned short*)(ws + (48ull << 20)); //  8 MiB (after GEMM1)

  f2b_kernel<<<4096, 256, 0, stream>>>(x, xb, 2048 * 2048);
  f2b_kernel<<<12288, 256, 0, stream>>>(Wa, wab, 6144 * 2048);

  // qkv = x @ W_attn^T : M=2048, N=6144, K=2048 — deep-pipelined 256^2 kernel
  gemm256<<<dim3(24, 8), 512, 0, stream>>>(xb, wab, qkvb, 2048, 6144, 2048);

  // causal flash attention: 1280 uniform 8-tile chunk items (heavy first)
  fa_kernel<<<1280, 256, 0, stream>>>(qkvb, Obuf, ML);

  // merge 1..4 chunk partials per (qt, h)
  fa_combine<<<512, 256, 0, stream>>>(Obuf, ML, attnb);

  // out = attn @ W_proj^T : M=2048, N=2048, K=2048 (A bf16, B fp32 fold, fp32 out)
  gemm_bt<unsigned short, float, true><<<dim3(16, 16), 256, 0, stream>>>(attnb, Wp, (void*)out, 2048, 2048, 2048);
}